// Round 1
// baseline (353.323 us; speedup 1.0000x reference)
//
#include <hip/hip_runtime.h>
#include <math.h>

// NetVLAD on MI355X, fp32 vector path (no fp32 MFMA on CDNA4).
// N=128 images, C=256 channels, K=64 clusters, P=1024 pixels.

#define C_DIM 256
#define K_CL  64
#define P_PIX 1024
#define CHUNK 256          // pixels per block (4 chunks per image)
#define SUB   32           // pixels per GEMM subtile
#define XS_LD (C_DIM + 8)  // 264: pad so per-lane c-vectors spread banks
#define A_LD  (K_CL + 4)   // 68:  pad so per-pixel rows spread banks

// ws layout (floats): [0,16384) = WT[c][k]; [16384, 16384+128*64) = asum[n][k]

__global__ void transpose_w(const float* __restrict__ w, float* __restrict__ wt) {
    int idx = blockIdx.x * 256 + threadIdx.x;   // 64 blocks -> 16384 elems
    int c = idx >> 6, k = idx & 63;
    wt[idx] = w[k * C_DIM + c];                 // WT[c*64 + k] = W[k][c]
}

__global__ __launch_bounds__(256) void netvlad_main(
    const float* __restrict__ x, const float* __restrict__ wt,
    const float* __restrict__ bias, float* __restrict__ out,
    float* __restrict__ asum_g) {
    __shared__ float xs[SUB][XS_LD];     // xnorm subtile, [p][c]
    __shared__ float a_lds[SUB][A_LD];   // softmax subtile, [p][k]
    __shared__ float rn_lds[CHUNK];      // per-pixel inverse norms

    const int t = threadIdx.x;
    const int n = blockIdx.x >> 2;
    const int chunk = blockIdx.x & 3;
    const size_t ximg = (size_t)n * C_DIM * P_PIX;
    const int p = chunk * CHUNK + t;          // this thread's pixel
    const float* xp = x + ximg + p;           // stride P_PIX over c

    // ---- Phase L: stream x once; raw logits (64 accums) + sum of squares.
    // WT row reads are wave-uniform -> scalar s_load_dwordx16 batches.
    float lg[K_CL];
    #pragma unroll
    for (int k = 0; k < K_CL; ++k) lg[k] = 0.f;
    float ss = 0.f;
    for (int c = 0; c < C_DIM; ++c) {
        const float xv = xp[(size_t)c * P_PIX];   // coalesced across lanes
        ss = fmaf(xv, xv, ss);
        const float* wr = wt + c * K_CL;          // uniform address
        #pragma unroll
        for (int k = 0; k < K_CL; ++k) lg[k] = fmaf(wr[k], xv, lg[k]);
    }
    const float rn = 1.f / fmaxf(sqrtf(ss), 1e-12f);
    rn_lds[t] = rn;

    // ---- softmax fully in-register (normalize folded in: logit = raw*rn + b)
    float mx = -3.402823466e38f;
    #pragma unroll
    for (int k = 0; k < K_CL; ++k) {
        lg[k] = fmaf(lg[k], rn, bias[k]);
        mx = fmaxf(mx, lg[k]);
    }
    float den = 0.f;
    #pragma unroll
    for (int k = 0; k < K_CL; ++k) { lg[k] = expf(lg[k] - mx); den += lg[k]; }
    const float inv = 1.f / den;
    #pragma unroll
    for (int k = 0; k < K_CL; ++k) lg[k] *= inv;   // lg[] is now a[k]

    // ---- Phase G: agg[k][c] += a[k][p] * xn[c][p] over this block's 256 pixels.
    float acc[8][8];
    #pragma unroll
    for (int i = 0; i < 8; ++i)
        #pragma unroll
        for (int j = 0; j < 8; ++j) acc[i][j] = 0.f;
    float asum_r = 0.f;
    const int k0 = (t >> 5) * 8;   // 8 k-rows per thread
    const int c0 = (t & 31) * 8;   // 8 c-cols per thread

    __syncthreads();  // rn_lds ready

    for (int sub = 0; sub < 8; ++sub) {
        // owning threads (pixels of this subtile) publish their a[]
        if ((t >> 5) == sub) {
            const int pr = t & 31;
            #pragma unroll
            for (int k = 0; k < K_CL; k += 4) {
                float4 v; v.x = lg[k]; v.y = lg[k+1]; v.z = lg[k+2]; v.w = lg[k+3];
                *(float4*)&a_lds[pr][k] = v;
            }
        }
        // cooperative re-load of x subtile (L2/L3-hot), scale by rn, transpose to [p][c]
        {
            const float* src = x + ximg + (size_t)t * P_PIX + chunk * CHUNK + sub * SUB;
            #pragma unroll
            for (int i4 = 0; i4 < 8; ++i4) {
                const float4 v = *(const float4*)&src[i4 * 4];
                const int pb = sub * SUB + i4 * 4;
                xs[i4*4+0][t] = v.x * rn_lds[pb+0];
                xs[i4*4+1][t] = v.y * rn_lds[pb+1];
                xs[i4*4+2][t] = v.z * rn_lds[pb+2];
                xs[i4*4+3][t] = v.w * rn_lds[pb+3];
            }
        }
        __syncthreads();

        for (int pp = 0; pp < SUB; ++pp) {
            const float4 a0 = *(const float4*)&a_lds[pp][k0];
            const float4 a1 = *(const float4*)&a_lds[pp][k0+4];
            const float4 x0 = *(const float4*)&xs[pp][c0];
            const float4 x1 = *(const float4*)&xs[pp][c0+4];
            const float av[8] = {a0.x,a0.y,a0.z,a0.w,a1.x,a1.y,a1.z,a1.w};
            const float xv[8] = {x0.x,x0.y,x0.z,x0.w,x1.x,x1.y,x1.z,x1.w};
            #pragma unroll
            for (int i = 0; i < 8; ++i)
                #pragma unroll
                for (int j = 0; j < 8; ++j)
                    acc[i][j] = fmaf(av[i], xv[j], acc[i][j]);
        }
        if (t < K_CL) {   // asum partial from the staged a tile
            #pragma unroll
            for (int pp = 0; pp < SUB; ++pp) asum_r += a_lds[pp][t];
        }
        __syncthreads();
    }

    // ---- publish partials (4 writers per cell)
    float* op = out + (size_t)n * K_CL * C_DIM;
    #pragma unroll
    for (int i = 0; i < 8; ++i)
        #pragma unroll
        for (int j = 0; j < 8; ++j)
            atomicAdd(&op[(k0 + i) * C_DIM + c0 + j], acc[i][j]);
    if (t < K_CL) atomicAdd(&asum_g[n * K_CL + t], asum_r);
}

__global__ __launch_bounds__(256) void netvlad_epi(
    float* __restrict__ out, const float* __restrict__ asum_g,
    const float* __restrict__ cent) {
    __shared__ float wred[4];
    __shared__ float gs_sh;
    const int n = blockIdx.x;
    const int t = threadIdx.x;
    const int k = t >> 2;          // 4 threads per cluster row
    const int q = t & 3;
    float* op = out + (size_t)n * 16384 + k * 256 + q * 64;
    const float* cp = cent + k * 256 + q * 64;
    const float as = asum_g[n * 64 + k];

    float v[64];
    float ss = 0.f;
    #pragma unroll
    for (int i = 0; i < 64; i += 4) {
        const float4 av = *(const float4*)&op[i];
        const float4 cv = *(const float4*)&cp[i];
        v[i+0] = fmaf(-as, cv.x, av.x);
        v[i+1] = fmaf(-as, cv.y, av.y);
        v[i+2] = fmaf(-as, cv.z, av.z);
        v[i+3] = fmaf(-as, cv.w, av.w);
        ss = fmaf(v[i+0], v[i+0], ss);
        ss = fmaf(v[i+1], v[i+1], ss);
        ss = fmaf(v[i+2], v[i+2], ss);
        ss = fmaf(v[i+3], v[i+3], ss);
    }
    // intra-norm: reduce over the 4 lanes sharing k
    ss += __shfl_xor(ss, 1);
    ss += __shfl_xor(ss, 2);
    const float iscale = 1.f / fmaxf(sqrtf(ss), 1e-12f);

    // global norm: sum of ss*iscale^2 over distinct k rows
    float g = (q == 0) ? ss * iscale * iscale : 0.f;
    #pragma unroll
    for (int off = 4; off < 64; off <<= 1) g += __shfl_xor(g, off);
    if ((t & 63) == 0) wred[t >> 6] = g;
    __syncthreads();
    if (t == 0) {
        const float tot = wred[0] + wred[1] + wred[2] + wred[3];
        gs_sh = 1.f / fmaxf(sqrtf(tot), 1e-12f);
    }
    __syncthreads();
    const float fs = iscale * gs_sh;
    #pragma unroll
    for (int i = 0; i < 64; i += 4) {
        float4 w4;
        w4.x = v[i+0] * fs; w4.y = v[i+1] * fs;
        w4.z = v[i+2] * fs; w4.w = v[i+3] * fs;
        *(float4*)&op[i] = w4;
    }
}

extern "C" void kernel_launch(void* const* d_in, const int* in_sizes, int n_in,
                              void* d_out, int out_size, void* d_ws, size_t ws_size,
                              hipStream_t stream) {
    (void)in_sizes; (void)n_in; (void)ws_size;
    const float* x    = (const float*)d_in[0];
    const float* w    = (const float*)d_in[1];
    const float* b    = (const float*)d_in[2];
    const float* cent = (const float*)d_in[3];
    float* out = (float*)d_out;
    float* wt     = (float*)d_ws;          // 16384 floats
    float* asum_g = wt + 16384;            // 8192 floats

    hipMemsetAsync(d_out, 0, (size_t)out_size * sizeof(float), stream);
    hipMemsetAsync(asum_g, 0, 128 * 64 * sizeof(float), stream);
    transpose_w<<<64, 256, 0, stream>>>(w, wt);
    netvlad_main<<<512, 256, 0, stream>>>(x, wt, b, out, asum_g);
    netvlad_epi<<<128, 256, 0, stream>>>(out, asum_g, cent);
}